// Round 3
// baseline (312.368 us; speedup 1.0000x reference)
//
#include <hip/hip_runtime.h>

typedef __attribute__((ext_vector_type(8))) __bf16 bf16x8;
typedef __attribute__((ext_vector_type(4))) float f32x4;
typedef __attribute__((ext_vector_type(4))) int i32x4;

__device__ __forceinline__ bf16x8 cvt8(f32x4 a, f32x4 b) {
    bf16x8 v;
    v[0] = (__bf16)a.x; v[1] = (__bf16)a.y; v[2] = (__bf16)a.z; v[3] = (__bf16)a.w;
    v[4] = (__bf16)b.x; v[5] = (__bf16)b.y; v[6] = (__bf16)b.z; v[7] = (__bf16)b.w;
    return v;
}

// ---------------------------------------------------------------------------
// Kernel 0: zero the 512KB accumulator + build graph offsets from sorted batch.
// ---------------------------------------------------------------------------
__global__ void prep(const int* __restrict__ batch, int nN,
                     float* __restrict__ sums, int* __restrict__ off)
{
    const int i = blockIdx.x * blockDim.x + threadIdx.x;
    const int stride = gridDim.x * blockDim.x;
    for (int t = i; t < 1024 * 128; t += stride) sums[t] = 0.f;
    for (int t = i; t < nN; t += stride) {
        const int b  = batch[t];
        const int bp = (t == 0) ? -1 : batch[t - 1];
        for (int g = bp + 1; g <= b; ++g) off[g] = t;
        if (t == nN - 1) {
            for (int g = b + 1; g <= 1024; ++g) off[g] = nN;
        }
    }
}

// ---------------------------------------------------------------------------
// Kernel 1: barrier-free. W (lin|gate) in LDS bf16, XOR-swizzled. Each wave
// owns a CONTIGUOUS range of P nodes, 16 per chunk, with 1-deep register
// prefetch of x + batch ids. Column-sums accumulate in registers per graph;
// atomics fire only at graph boundaries / wave end.
// ---------------------------------------------------------------------------
__global__ __launch_bounds__(256, 2) void gnn_main(
    const float* __restrict__ x, const int* __restrict__ batch,
    const float* __restrict__ Wlin, const float* __restrict__ blin,
    const float* __restrict__ Wgate, const float* __restrict__ bgate,
    float* __restrict__ sums, int nN, int P)
{
    __shared__ __bf16 Wlds[256 * 128];   // 64 KB

    const int tid  = threadIdx.x;
    const int lane = tid & 63;
    const int w    = tid >> 6;    // wave 0..3
    const int l15  = lane & 15;
    const int lg   = lane >> 4;   // 0..3

    // ---- stage W -> LDS (bf16, swizzle: byte ^= (col&7)<<4)
    for (int idx = tid; idx < 4096; idx += 256) {
        const int c  = idx >> 4;      // col 0..255  (0-127 lin, 128-255 gate)
        const int kg = idx & 15;      // 8-elem k group
        const float* src = (c < 128 ? Wlin + (size_t)c * 128
                                    : Wgate + (size_t)(c - 128) * 128) + kg * 8;
        f32x4 u0 = *(const f32x4*)src;
        f32x4 u1 = *(const f32x4*)(src + 4);
        const int byte = (c * 256 + kg * 16) ^ ((c & 7) << 4);
        *(bf16x8*)((char*)Wlds + byte) = cvt8(u0, u1);
    }

    float bl[8], bg[8];
#pragma unroll
    for (int j = 0; j < 8; ++j) {
        bl[j] = blin[j * 16 + l15];
        bg[j] = bgate[j * 16 + l15];
    }
    __syncthreads();   // the ONLY barrier

    const int wid = blockIdx.x * 4 + w;
    const long r0 = (long)wid * P;
    if (r0 >= nN) return;
    const int R0 = (int)r0;
    const int R1 = min(R0 + P, nN);
    const int nc = (R1 - R0 + 15) >> 4;

    int   gcur = batch[R0];
    float racc[8];
#pragma unroll
    for (int j = 0; j < 8; ++j) racc[j] = 0.f;

    auto flush = [&](int g) {
#pragma unroll
        for (int j = 0; j < 8; ++j) {
            float cs = racc[j];
            cs += __shfl_xor(cs, 16);
            cs += __shfl_xor(cs, 32);
            if (lg == 0) atomicAdd(sums + (size_t)g * 128 + j * 16 + l15, cs);
            racc[j] = 0.f;
        }
    };

    // ---- prefetch registers
    f32x4 pf[8];
    i32x4 bv;
    auto issue = [&](int base) {
        const int node = base + l15;
        const float* xr = x + (size_t)(node < nN ? node : nN - 1) * 128 + lg * 8;
#pragma unroll
        for (int kk = 0; kk < 4; ++kk) {
            pf[2 * kk]     = *(const f32x4*)(xr + kk * 32);
            pf[2 * kk + 1] = *(const f32x4*)(xr + kk * 32 + 4);
        }
        const int ba = base + lg * 4;
        bv = *(const i32x4*)(batch + (ba <= nN - 4 ? ba : nN - 4));
    };

    issue(R0);
    bf16x8 afr[4];
#pragma unroll
    for (int kk = 0; kk < 4; ++kk) afr[kk] = cvt8(pf[2 * kk], pf[2 * kk + 1]);
    i32x4 bcur = bv;

    for (int c = 0; c < nc; ++c) {
        const int base = R0 + (c << 4);
        const bool more = (c + 1 < nc);
        if (more) issue(base + 16);          // loads in flight during GEMMs

        // ---- pass 1: gate GEMM (cols 128..255)
        f32x4 e[8];
#pragma unroll
        for (int j = 0; j < 8; ++j) e[j] = (f32x4)0.f;
#pragma unroll
        for (int kk = 0; kk < 4; ++kk) {
#pragma unroll
            for (int j = 0; j < 8; ++j) {
                const int col  = 128 + j * 16 + l15;
                const int byte = (col * 256 + kk * 64 + lg * 16) ^ ((col & 7) << 4);
                bf16x8 bfr = *(const bf16x8*)((const char*)Wlds + byte);
                e[j] = __builtin_amdgcn_mfma_f32_16x16x32_bf16(afr[kk], bfr, e[j], 0, 0, 0);
            }
        }

        // ---- in-wave softmax (row = lg*4 + r)
        f32x4 ps = (f32x4)0.f;
#pragma unroll
        for (int j = 0; j < 8; ++j) {
#pragma unroll
            for (int r = 0; r < 4; ++r) {
                float t = __expf(e[j][r] + bg[j]);
                e[j][r] = t;
                ps[r] += t;
            }
        }
        float inv[4];
#pragma unroll
        for (int r = 0; r < 4; ++r) {
            float p = ps[r];
            p += __shfl_xor(p, 1);
            p += __shfl_xor(p, 2);
            p += __shfl_xor(p, 4);
            p += __shfl_xor(p, 8);
            inv[r] = 1.0f / p;
        }

        // ---- pass 2: state GEMM (cols 0..127)
        f32x4 s[8];
#pragma unroll
        for (int j = 0; j < 8; ++j) s[j] = (f32x4)0.f;
#pragma unroll
        for (int kk = 0; kk < 4; ++kk) {
#pragma unroll
            for (int j = 0; j < 8; ++j) {
                const int col  = j * 16 + l15;
                const int byte = (col * 256 + kk * 64 + lg * 16) ^ ((col & 7) << 4);
                bf16x8 bfr = *(const bf16x8*)((const char*)Wlds + byte);
                s[j] = __builtin_amdgcn_mfma_f32_16x16x32_bf16(afr[kk], bfr, s[j], 0, 0, 0);
            }
        }

        // ---- gated values
#pragma unroll
        for (int j = 0; j < 8; ++j) {
#pragma unroll
            for (int r = 0; r < 4; ++r) {
                s[j][r] = (s[j][r] + bl[j]) * e[j][r] * inv[r];
            }
        }

        // ---- per-graph register accumulation (rows: base + lg*4 + r)
        int bC[4];
#pragma unroll
        for (int r = 0; r < 4; ++r) {
            bC[r] = (base + lg * 4 + r < R1) ? bcur[r] : -1;
        }
        const bool ok = (bC[0] == gcur) & (bC[1] == gcur) &
                        (bC[2] == gcur) & (bC[3] == gcur);
        if (__all(ok)) {
#pragma unroll
            for (int j = 0; j < 8; ++j)
                racc[j] += s[j][0] + s[j][1] + s[j][2] + s[j][3];
        } else {
            int mx = max(max(bC[0], bC[1]), max(bC[2], bC[3]));
            mx = max(mx, __shfl_xor(mx, 16));
            mx = max(mx, __shfl_xor(mx, 32));
            for (int g = gcur; g <= mx; ++g) {
#pragma unroll
                for (int j = 0; j < 8; ++j) {
                    float a = 0.f;
#pragma unroll
                    for (int r = 0; r < 4; ++r) a += (bC[r] == g) ? s[j][r] : 0.f;
                    racc[j] += a;
                }
                if (g < mx) flush(g);
            }
            gcur = mx;
        }

        // ---- rotate prefetch into A fragments (waits happen here, late)
        if (more) {
#pragma unroll
            for (int kk = 0; kk < 4; ++kk) afr[kk] = cvt8(pf[2 * kk], pf[2 * kk + 1]);
            bcur = bv;
        }
    }
    flush(gcur);
}

// ---------------------------------------------------------------------------
// Kernel 2: mean = sums/count, out = mean @ Wf^T + bf
// ---------------------------------------------------------------------------
__global__ __launch_bounds__(128) void final_mm(
    const float* __restrict__ sums, const int* __restrict__ off,
    const float* __restrict__ Wf, const float* __restrict__ bf,
    float* __restrict__ out)
{
    const int g = blockIdx.x, c = threadIdx.x;
    __shared__ float m[128];
    const int cnt = off[g + 1] - off[g];
    const float invC = 1.0f / (float)(cnt > 0 ? cnt : 1);
    m[c] = sums[g * 128 + c] * invC;
    __syncthreads();
    float acc = bf[c];
    const f32x4* wr = (const f32x4*)(Wf + (size_t)c * 128);
#pragma unroll
    for (int k = 0; k < 32; ++k) {
        f32x4 wv = wr[k];
        acc += m[4 * k] * wv.x + m[4 * k + 1] * wv.y + m[4 * k + 2] * wv.z + m[4 * k + 3] * wv.w;
    }
    out[g * 128 + c] = acc;
}

extern "C" void kernel_launch(void* const* d_in, const int* in_sizes, int n_in,
                              void* d_out, int out_size, void* d_ws, size_t ws_size,
                              hipStream_t stream)
{
    const float* x     = (const float*)d_in[0];
    const int*   batch = (const int*)d_in[1];
    const float* Wlin  = (const float*)d_in[2];
    const float* blin  = (const float*)d_in[3];
    const float* Wgate = (const float*)d_in[4];
    const float* bgate = (const float*)d_in[5];
    const float* Wfin  = (const float*)d_in[6];
    const float* bfin  = (const float*)d_in[7];
    float* out  = (float*)d_out;
    float* sums = (float*)d_ws;                               // 512 KB
    int*   off  = (int*)((char*)d_ws + 512 * 1024);           // 1025 ints

    const int nNodes  = in_sizes[1];
    const int nGraphs = out_size / 128;

    // 2048 waves (512 blocks x 4), contiguous per-wave ranges, multiple of 16
    const int P = (((nNodes + 2047) / 2048) + 15) & ~15;

    prep<<<2048, 256, 0, stream>>>(batch, nNodes, sums, off);
    gnn_main<<<512, 256, 0, stream>>>(x, batch, Wlin, blin, Wgate, bgate, sums, nNodes, P);
    final_mm<<<nGraphs, 128, 0, stream>>>(sums, off, Wfin, bfin, out);
}

// Round 4
// 179.547 us; speedup vs baseline: 1.7398x; 1.7398x over previous
//
#include <hip/hip_runtime.h>

typedef __attribute__((ext_vector_type(8))) __bf16 bf16x8;
typedef __attribute__((ext_vector_type(4))) float f32x4;

__device__ __forceinline__ bf16x8 cvt8(f32x4 a, f32x4 b) {
    bf16x8 v;
    v[0] = (__bf16)a.x; v[1] = (__bf16)a.y; v[2] = (__bf16)a.z; v[3] = (__bf16)a.w;
    v[4] = (__bf16)b.x; v[5] = (__bf16)b.y; v[6] = (__bf16)b.z; v[7] = (__bf16)b.w;
    return v;
}

// raw barrier: drains LDS ops only — leaves global prefetch loads in flight
// (a __syncthreads would emit s_waitcnt vmcnt(0) and kill the prefetch)
__device__ __forceinline__ void bar_lgkm() {
    asm volatile("s_waitcnt lgkmcnt(0)\n\ts_barrier" ::: "memory");
}

// ---------------------------------------------------------------------------
// Kernel 0: zero 512KB accumulator + build graph offsets from sorted batch.
// ---------------------------------------------------------------------------
__global__ void prep(const int* __restrict__ batch, int nN,
                     float* __restrict__ sums, int* __restrict__ off)
{
    const int i = blockIdx.x * blockDim.x + threadIdx.x;
    const int stride = gridDim.x * blockDim.x;
    for (int t = i; t < 1024 * 128; t += stride) sums[t] = 0.f;
    for (int t = i; t < nN; t += stride) {
        const int b  = batch[t];
        const int bp = (t == 0) ? -1 : batch[t - 1];
        for (int g = bp + 1; g <= b; ++g) off[g] = t;
        if (t == nN - 1) {
            for (int g = b + 1; g <= 1024; ++g) off[g] = nN;
        }
    }
}

// ---------------------------------------------------------------------------
// Kernel 1: 512 threads / 8 waves per block. Wave w owns output cols
// [16w,16w+16) of BOTH states and gates (W frags in 32 VGPR). x tiles of 64
// nodes staged f32->bf16 into double-buffered swizzled LDS with a 1-tile
// register prefetch. Two raw lgkm barriers per tile. Per-graph column sums
// accumulate in registers; atomics only at graph boundaries.
// ---------------------------------------------------------------------------
__global__ __launch_bounds__(512, 4) void gnn_main(
    const float* __restrict__ x, const int* __restrict__ batch,
    const float* __restrict__ Wlin, const float* __restrict__ blin,
    const float* __restrict__ Wgate, const float* __restrict__ bgate,
    float* __restrict__ sums, int nN, int P)
{
    __shared__ __bf16 buf[2][64 * 128];   // 2 x 16 KB, XOR-swizzled
    __shared__ float  PS[8][72];          // per-wave row partial sums (padded)
    __shared__ float  invLds[64];         // per-row 1/sum

    const int tid  = threadIdx.x;
    const int lane = tid & 63;
    const int w    = tid >> 6;    // wave 0..7
    const int l15  = lane & 15;
    const int lg   = lane >> 4;   // 0..3

    const int R0 = blockIdx.x * P;
    if (R0 >= nN) return;
    const int R1b = min(R0 + P, nN);
    const int nt  = (R1b - R0 + 63) >> 6;

    // ---- W fragments (B operand): rows [16w, 16w+16) of Wlin / Wgate
    bf16x8 bfrag[2][4];
    {
        const float* Wp0 = Wlin  + (size_t)(w * 16 + l15) * 128 + lg * 8;
        const float* Wp1 = Wgate + (size_t)(w * 16 + l15) * 128 + lg * 8;
#pragma unroll
        for (int kk = 0; kk < 4; ++kk) {
            bfrag[0][kk] = cvt8(*(const f32x4*)(Wp0 + kk * 32),
                                *(const f32x4*)(Wp0 + kk * 32 + 4));
            bfrag[1][kk] = cvt8(*(const f32x4*)(Wp1 + kk * 32),
                                *(const f32x4*)(Wp1 + kk * 32 + 4));
        }
    }
    const float bl = blin[w * 16 + l15];
    const float bg = bgate[w * 16 + l15];

    // ---- staging mapping: lane covers x[base + (tid>>3)][(tid&7)*16 .. +15]
    const int srow = tid >> 3;
    const int skc  = tid & 7;

    f32x4 pf[4];
    int   btn;
    auto issue = [&](int base) {
        const int nd  = base + srow;
        const float* p = x + (size_t)(nd < nN ? nd : nN - 1) * 128 + skc * 16;
        pf[0] = *(const f32x4*)(p);
        pf[1] = *(const f32x4*)(p + 4);
        pf[2] = *(const f32x4*)(p + 8);
        pf[3] = *(const f32x4*)(p + 12);
        const int bi = base + lane;
        btn = (bi < nN) ? batch[bi] : -1;
    };
    auto stage = [&](int bsel) {
        const int lin = srow * 256 + skc * 32;
        const int sw  = (srow & 7) << 4;
        *(bf16x8*)((char*)buf[bsel] + ((lin) ^ sw))      = cvt8(pf[0], pf[1]);
        *(bf16x8*)((char*)buf[bsel] + ((lin + 16) ^ sw)) = cvt8(pf[2], pf[3]);
    };

    float racc = 0.f;
    auto flush = [&](int g) {
        float v = racc;
        v += __shfl_xor(v, 16);
        v += __shfl_xor(v, 32);
        if (lg == 0) atomicAdd(sums + (size_t)g * 128 + w * 16 + l15, v);
        racc = 0.f;
    };

    // ---- prologue: tile 0
    issue(R0);
    int bt = btn;
    stage(0);
    bar_lgkm();

    int gcur = __shfl(bt, 0);

    for (int t = 0; t < nt; ++t) {
        const int base = R0 + (t << 6);
        const bool more = (t + 1 < nt);
        if (more) issue(base + 64);      // prefetch next tile (stays in flight)

        // ---- fused dual GEMM over this tile
        f32x4 accS[4], accG[4];
#pragma unroll
        for (int r16 = 0; r16 < 4; ++r16) { accS[r16] = (f32x4)0.f; accG[r16] = (f32x4)0.f; }
        const char* bc = (const char*)buf[t & 1];
#pragma unroll
        for (int kk = 0; kk < 4; ++kk) {
            bf16x8 af[4];
#pragma unroll
            for (int r16 = 0; r16 < 4; ++r16) {
                const int row = r16 * 16 + l15;
                const int off = (row * 256 + kk * 64 + lg * 16) ^ ((row & 7) << 4);
                af[r16] = *(const bf16x8*)(bc + off);
            }
#pragma unroll
            for (int r16 = 0; r16 < 4; ++r16) {
                accS[r16] = __builtin_amdgcn_mfma_f32_16x16x32_bf16(af[r16], bfrag[0][kk], accS[r16], 0, 0, 0);
                accG[r16] = __builtin_amdgcn_mfma_f32_16x16x32_bf16(af[r16], bfrag[1][kk], accG[r16], 0, 0, 0);
            }
        }

        // ---- exp + per-wave row partials (reduce over l15) -> PS
#pragma unroll
        for (int r16 = 0; r16 < 4; ++r16) {
            f32x4 p;
#pragma unroll
            for (int r = 0; r < 4; ++r) {
                float e = __expf(accG[r16][r] + bg);
                accG[r16][r] = e;
                p[r] = e;
            }
#pragma unroll
            for (int d = 1; d <= 8; d <<= 1) {
#pragma unroll
                for (int r = 0; r < 4; ++r) p[r] += __shfl_xor(p[r], d);
            }
            if (l15 == 0) *(f32x4*)&PS[w][r16 * 16 + lg * 4] = p;
        }
        bar_lgkm();   // B1: PS visible

        // ---- stage 2: total row sums (wave w handles rows [8w, 8w+8))
        {
            float v = PS[lane >> 3][w * 8 + (lane & 7)];
            v += __shfl_xor(v, 8);
            v += __shfl_xor(v, 16);
            v += __shfl_xor(v, 32);
            if (lane < 8) invLds[w * 8 + lane] = 1.0f / v;
        }
        if (more) stage((t + 1) & 1);    // waits own pf (compiler-counted vmcnt)
        bar_lgkm();   // B2: invLds + next x-tile visible

        // ---- gating
#pragma unroll
        for (int r16 = 0; r16 < 4; ++r16) {
            f32x4 iv = *(const f32x4*)&invLds[r16 * 16 + lg * 4];
#pragma unroll
            for (int r = 0; r < 4; ++r)
                accS[r16][r] = (accS[r16][r] + bl) * accG[r16][r] * iv[r];
        }

        // ---- segmented per-graph accumulation (rows base..base+63, sorted)
        const int nvalid = min(64, nN - base);
        const int gf = __shfl(bt, 0);
        const int gl = __shfl(bt, nvalid - 1);
        if (nvalid == 64 && gf == gl) {
            if (gf != gcur) { flush(gcur); gcur = gf; }
            float ts = 0.f;
#pragma unroll
            for (int r16 = 0; r16 < 4; ++r16)
#pragma unroll
                for (int r = 0; r < 4; ++r) ts += accS[r16][r];
            racc += ts;
        } else {
            int brow[4][4];
#pragma unroll
            for (int r16 = 0; r16 < 4; ++r16)
#pragma unroll
                for (int r = 0; r < 4; ++r)
                    brow[r16][r] = __shfl(bt, r16 * 16 + lg * 4 + r);
            for (int g = gf; g <= gl; ++g) {
                float cs = 0.f;
#pragma unroll
                for (int r16 = 0; r16 < 4; ++r16)
#pragma unroll
                    for (int r = 0; r < 4; ++r)
                        cs += (brow[r16][r] == g) ? accS[r16][r] : 0.f;
                if (g == gcur) racc += cs;
                else { flush(gcur); gcur = g; racc = cs; }
            }
        }
        bt = btn;
    }
    flush(gcur);
}

// ---------------------------------------------------------------------------
// Kernel 2: mean = sums/count, out = mean @ Wf^T + bf
// ---------------------------------------------------------------------------
__global__ __launch_bounds__(128) void final_mm(
    const float* __restrict__ sums, const int* __restrict__ off,
    const float* __restrict__ Wf, const float* __restrict__ bf,
    float* __restrict__ out)
{
    const int g = blockIdx.x, c = threadIdx.x;
    __shared__ float m[128];
    const int cnt = off[g + 1] - off[g];
    const float invC = 1.0f / (float)(cnt > 0 ? cnt : 1);
    m[c] = sums[g * 128 + c] * invC;
    __syncthreads();
    float acc = bf[c];
    const f32x4* wr = (const f32x4*)(Wf + (size_t)c * 128);
#pragma unroll
    for (int k = 0; k < 32; ++k) {
        f32x4 wv = wr[k];
        acc += m[4 * k] * wv.x + m[4 * k + 1] * wv.y + m[4 * k + 2] * wv.z + m[4 * k + 3] * wv.w;
    }
    out[g * 128 + c] = acc;
}

extern "C" void kernel_launch(void* const* d_in, const int* in_sizes, int n_in,
                              void* d_out, int out_size, void* d_ws, size_t ws_size,
                              hipStream_t stream)
{
    const float* x     = (const float*)d_in[0];
    const int*   batch = (const int*)d_in[1];
    const float* Wlin  = (const float*)d_in[2];
    const float* blin  = (const float*)d_in[3];
    const float* Wgate = (const float*)d_in[4];
    const float* bgate = (const float*)d_in[5];
    const float* Wfin  = (const float*)d_in[6];
    const float* bfin  = (const float*)d_in[7];
    float* out  = (float*)d_out;
    float* sums = (float*)d_ws;                               // 512 KB
    int*   off  = (int*)((char*)d_ws + 512 * 1024);           // 1025 ints

    const int nNodes  = in_sizes[1];
    const int nGraphs = out_size / 128;

    // ~512 resident-block slots (2 per CU): P multiple of 64
    const int P  = ((((nNodes + 511) / 512) + 63) & ~63);
    const int nB = (nNodes + P - 1) / P;

    prep<<<2048, 256, 0, stream>>>(batch, nNodes, sums, off);
    gnn_main<<<nB, 512, 0, stream>>>(x, batch, Wlin, blin, Wgate, bgate, sums, nNodes, P);
    final_mm<<<nGraphs, 128, 0, stream>>>(sums, off, Wfin, bfin, out);
}

// Round 5
// 135.196 us; speedup vs baseline: 2.3105x; 1.3280x over previous
//
#include <hip/hip_runtime.h>

typedef __attribute__((ext_vector_type(8))) __bf16 bf16x8;
typedef __attribute__((ext_vector_type(4))) float f32x4;

typedef __attribute__((address_space(3))) unsigned int as3u32;
typedef __attribute__((address_space(1))) const unsigned int as1u32;

__device__ __forceinline__ bf16x8 cvt8(f32x4 a, f32x4 b) {
    bf16x8 v;
    v[0] = (__bf16)a.x; v[1] = (__bf16)a.y; v[2] = (__bf16)a.z; v[3] = (__bf16)a.w;
    v[4] = (__bf16)b.x; v[5] = (__bf16)b.y; v[6] = (__bf16)b.z; v[7] = (__bf16)b.w;
    return v;
}

// ---------------------------------------------------------------------------
// Kernel 0: zero 512KB accumulator + build graph offsets from sorted batch.
// ---------------------------------------------------------------------------
__global__ void prep(const int* __restrict__ batch, int nN,
                     float* __restrict__ sums, int* __restrict__ off)
{
    const int i = blockIdx.x * blockDim.x + threadIdx.x;
    const int stride = gridDim.x * blockDim.x;
    for (int t = i; t < 1024 * 128; t += stride) sums[t] = 0.f;
    for (int t = i; t < nN; t += stride) {
        const int b  = batch[t];
        const int bp = (t == 0) ? -1 : batch[t - 1];
        for (int g = bp + 1; g <= b; ++g) off[g] = t;
        if (t == nN - 1) {
            for (int g = b + 1; g <= 1024; ++g) off[g] = nN;
        }
    }
}

// ---------------------------------------------------------------------------
// Kernel 1: 512 thr / 8 waves. Wave w owns cols [16w,16w+16) of both states
// and gates. x staged as f32 via global_load_lds (no staging VGPRs -> no
// spill), double-buffered, source-pre-swizzled 16B XOR. f32->bf16 convert at
// fragment read. Two raw barriers per tile (lgkm / vm+lgkm). Per-graph column
// sums accumulate in registers; atomics only at graph boundaries.
// ---------------------------------------------------------------------------
__global__ __launch_bounds__(512, 4) void gnn_main(
    const float* __restrict__ x, const int* __restrict__ batch,
    const float* __restrict__ Wlin, const float* __restrict__ blin,
    const float* __restrict__ Wgate, const float* __restrict__ bgate,
    float* __restrict__ sums, int nN, int P)
{
    __shared__ float bufA[2][64 * 128];   // 2 x 32 KB f32, 16B-XOR swizzled
    __shared__ float PS[8][72];           // per-wave row partial sums (padded)
    __shared__ float invLds[64];          // per-row 1/sum

    const int tid  = threadIdx.x;
    const int lane = tid & 63;
    const int w    = tid >> 6;    // wave 0..7
    const int l15  = lane & 15;
    const int lg   = lane >> 4;   // 0..3

    const int R0 = blockIdx.x * P;
    if (R0 >= nN) return;
    const int R1b = min(R0 + P, nN);
    const int nt  = (R1b - R0 + 63) >> 6;

    // ---- W fragments (B operand): rows [16w,16w+16) of Wlin / Wgate
    bf16x8 bfrag[2][4];
    {
        const float* Wp0 = Wlin  + (size_t)(w * 16 + l15) * 128 + lg * 8;
        const float* Wp1 = Wgate + (size_t)(w * 16 + l15) * 128 + lg * 8;
#pragma unroll
        for (int kk = 0; kk < 4; ++kk) {
            bfrag[0][kk] = cvt8(*(const f32x4*)(Wp0 + kk * 32),
                                *(const f32x4*)(Wp0 + kk * 32 + 4));
            bfrag[1][kk] = cvt8(*(const f32x4*)(Wp1 + kk * 32),
                                *(const f32x4*)(Wp1 + kk * 32 + 4));
        }
    }
    const float bl = blin[w * 16 + l15];
    const float bg = bgate[w * 16 + l15];

    // ---- staging: thread covers 4x 16B chunks; LDS dest linear, global
    // source pre-swizzled so LDS[row][b] = x[row][b ^ ((row&7)<<4)]
    const int srh = tid >> 5;          // row within 16-row group
    const int sb  = (tid & 31) * 16;   // byte within 512B row
    int btn;
    auto STAGE = [&](int bsel, int base) {
#pragma unroll
        for (int i = 0; i < 4; ++i) {
            const int row = i * 16 + srh;
            const int nd  = base + row;
            const int ndc = nd < nN ? nd : nN - 1;
            const int bsw = sb ^ ((row & 7) << 4);
            const float* src = x + (size_t)ndc * 128 + (bsw >> 2);
            char* dst = (char*)&bufA[bsel][0] + i * 8192 + tid * 16;
            __builtin_amdgcn_global_load_lds((as1u32*)src, (as3u32*)dst, 16, 0, 0);
        }
        const int bi = base + lane;
        btn = (bi < nN) ? batch[bi] : -1;
    };

    float racc = 0.f;
    int   gcur = batch[R0];
    auto flush = [&](int g) {
        float v = racc;
        v += __shfl_xor(v, 16);
        v += __shfl_xor(v, 32);
        if (lg == 0) atomicAdd(sums + (size_t)g * 128 + w * 16 + l15, v);
        racc = 0.f;
    };

    // ---- prologue
    STAGE(0, R0);
    int bt = btn;
    asm volatile("s_waitcnt vmcnt(0)\n\ts_barrier" ::: "memory");

    for (int t = 0; t < nt; ++t) {
        const int base = R0 + (t << 6);
        const bool more = (t + 1 < nt);
        if (more) STAGE((t + 1) & 1, base + 64);   // in flight through GEMMs

        // ---- fused dual GEMM from f32 LDS tile (convert per fragment)
        f32x4 accS[4], accG[4];
#pragma unroll
        for (int r16 = 0; r16 < 4; ++r16) { accS[r16] = (f32x4)0.f; accG[r16] = (f32x4)0.f; }
        const char* bc = (const char*)&bufA[t & 1][0];
#pragma unroll
        for (int kk = 0; kk < 4; ++kk) {
#pragma unroll
            for (int r16 = 0; r16 < 4; ++r16) {
                const int row = r16 * 16 + l15;
                const int sw  = (row & 7) << 4;
                const int byt = row * 512 + kk * 128 + lg * 32;
                f32x4 u0 = *(const f32x4*)(bc + ((byt) ^ sw));
                f32x4 u1 = *(const f32x4*)(bc + ((byt + 16) ^ sw));
                bf16x8 af = cvt8(u0, u1);
                accS[r16] = __builtin_amdgcn_mfma_f32_16x16x32_bf16(af, bfrag[0][kk], accS[r16], 0, 0, 0);
                accG[r16] = __builtin_amdgcn_mfma_f32_16x16x32_bf16(af, bfrag[1][kk], accG[r16], 0, 0, 0);
            }
        }

        // ---- exp + per-wave row partials (reduce over l15) -> PS
#pragma unroll
        for (int r16 = 0; r16 < 4; ++r16) {
            f32x4 p;
#pragma unroll
            for (int r = 0; r < 4; ++r) {
                float e = __expf(accG[r16][r] + bg);
                accG[r16][r] = e;
                p[r] = e;
            }
#pragma unroll
            for (int d = 1; d <= 8; d <<= 1) {
#pragma unroll
                for (int r = 0; r < 4; ++r) p[r] += __shfl_xor(p[r], d);
            }
            if (l15 == 0) *(f32x4*)&PS[w][r16 * 16 + lg * 4] = p;
        }
        asm volatile("s_waitcnt lgkmcnt(0)\n\ts_barrier" ::: "memory");  // B1

        // ---- stage 2: total row sums (wave w -> rows [8w,8w+8))
        {
            float v = PS[lane >> 3][w * 8 + (lane & 7)];
            v += __shfl_xor(v, 8);
            v += __shfl_xor(v, 16);
            v += __shfl_xor(v, 32);
            if (lane < 8) invLds[w * 8 + lane] = 1.0f / v;
        }
        // B2: invLds visible AND next f32 tile fully landed in LDS
        asm volatile("s_waitcnt vmcnt(0) lgkmcnt(0)\n\ts_barrier" ::: "memory");

        // ---- gating
#pragma unroll
        for (int r16 = 0; r16 < 4; ++r16) {
            f32x4 iv = *(const f32x4*)&invLds[r16 * 16 + lg * 4];
#pragma unroll
            for (int r = 0; r < 4; ++r)
                accS[r16][r] = (accS[r16][r] + bl) * accG[r16][r] * iv[r];
        }

        // ---- segmented per-graph accumulation (rows base..base+63, sorted)
        const int nvalid = min(64, nN - base);
        const int gf = __shfl(bt, 0);
        const int gl = __shfl(bt, nvalid - 1);
        if (nvalid == 64 && gf == gl) {
            if (gf != gcur) { flush(gcur); gcur = gf; }
            float ts = 0.f;
#pragma unroll
            for (int r16 = 0; r16 < 4; ++r16)
#pragma unroll
                for (int r = 0; r < 4; ++r) ts += accS[r16][r];
            racc += ts;
        } else {
            for (int g = gf; g <= gl; ++g) {
                float cs = 0.f;
#pragma unroll
                for (int r16 = 0; r16 < 4; ++r16)
#pragma unroll
                    for (int r = 0; r < 4; ++r) {
                        const int bid = __shfl(bt, r16 * 16 + lg * 4 + r);
                        cs += (bid == g) ? accS[r16][r] : 0.f;
                    }
                if (g == gcur) racc += cs;
                else { flush(gcur); gcur = g; racc = cs; }
            }
        }
        bt = btn;
    }
    flush(gcur);
}

// ---------------------------------------------------------------------------
// Kernel 2: mean = sums/count, out = mean @ Wf^T + bf
// ---------------------------------------------------------------------------
__global__ __launch_bounds__(128) void final_mm(
    const float* __restrict__ sums, const int* __restrict__ off,
    const float* __restrict__ Wf, const float* __restrict__ bf,
    float* __restrict__ out)
{
    const int g = blockIdx.x, c = threadIdx.x;
    __shared__ float m[128];
    const int cnt = off[g + 1] - off[g];
    const float invC = 1.0f / (float)(cnt > 0 ? cnt : 1);
    m[c] = sums[g * 128 + c] * invC;
    __syncthreads();
    float acc = bf[c];
    const f32x4* wr = (const f32x4*)(Wf + (size_t)c * 128);
#pragma unroll
    for (int k = 0; k < 32; ++k) {
        f32x4 wv = wr[k];
        acc += m[4 * k] * wv.x + m[4 * k + 1] * wv.y + m[4 * k + 2] * wv.z + m[4 * k + 3] * wv.w;
    }
    out[g * 128 + c] = acc;
}

extern "C" void kernel_launch(void* const* d_in, const int* in_sizes, int n_in,
                              void* d_out, int out_size, void* d_ws, size_t ws_size,
                              hipStream_t stream)
{
    const float* x     = (const float*)d_in[0];
    const int*   batch = (const int*)d_in[1];
    const float* Wlin  = (const float*)d_in[2];
    const float* blin  = (const float*)d_in[3];
    const float* Wgate = (const float*)d_in[4];
    const float* bgate = (const float*)d_in[5];
    const float* Wfin  = (const float*)d_in[6];
    const float* bfin  = (const float*)d_in[7];
    float* out  = (float*)d_out;
    float* sums = (float*)d_ws;                               // 512 KB
    int*   off  = (int*)((char*)d_ws + 512 * 1024);           // 1025 ints

    const int nNodes  = in_sizes[1];
    const int nGraphs = out_size / 128;

    // ~489 blocks (2 resident/CU), contiguous ranges, P multiple of 64
    const int P  = ((((nNodes + 511) / 512) + 63) & ~63);
    const int nB = (nNodes + P - 1) / P;

    prep<<<2048, 256, 0, stream>>>(batch, nNodes, sums, off);
    gnn_main<<<nB, 512, 0, stream>>>(x, batch, Wlin, blin, Wgate, bgate, sums, nNodes, P);
    final_mm<<<nGraphs, 128, 0, stream>>>(sums, off, Wfin, bfin, out);
}